// Round 8
// baseline (12274.879 us; speedup 1.0000x reference)
//
#include <hip/hip_runtime.h>

#define N_NODES 100000
#define N_EDGES 3200000
#define NDB 782         // dst blocks of 128 nodes: ceil(100000/128)
#define NT 13           // src tiles of 8192 nodes: ceil(100000/8192)
#define NKEY (NDB * NT) // 10166 sub-buckets
#define BCAP 640        // per-sub-bucket capacity (avg 315, +18 sigma)
#define CNTSTRIDE 16    // pad cursors to one per 64B line

typedef unsigned int uint;
typedef __attribute__((ext_vector_type(4))) uint u4v;
typedef __attribute__((ext_vector_type(8))) short s8v;   // 8 bf16 (4 VGPRs)
typedef __attribute__((ext_vector_type(4))) float f32x4; // mfma acc

// ---------- edge partition: single-pass capacity-padded scatter ----------

// edge_index may be int64 (reference decl) or int32. Values < 2^17, so if
// int64 the odd dwords are zero; prob of 4 consecutive int32 srcs == 0 ~ 0.
__global__ void detect_fmt(const uint* __restrict__ e, int* __restrict__ flag) {
    if (threadIdx.x == 0)
        *flag = (e[1] == 0u && e[3] == 0u && e[5] == 0u && e[7] == 0u) ? 1 : 0;
}

__device__ __forceinline__ int load_idx(const void* edges, int fmt, long long i) {
    return fmt ? (int)((const long long*)edges)[i] : ((const int*)edges)[i];
}

// Each edge -> sub-bucket (dst_block, src_tile). Global atomic cursors, padded
// to 64B each (10166 ctrs, ~315 adds/ctr spread over the kernel: no hot line).
__global__ __launch_bounds__(256) void scatter_direct(const void* __restrict__ edges,
                                                      const int* __restrict__ flag,
                                                      int* __restrict__ cnt,
                                                      uint* __restrict__ elist) {
    int i = blockIdx.x * 256 + threadIdx.x;
    if (i >= N_EDGES) return;
    int fmt = *flag;
    int src = load_idx(edges, fmt, i);
    int dst = load_idx(edges, fmt, (long long)N_EDGES + i);
    int key = (dst >> 7) * NT + (src >> 13);
    int pos = atomicAdd(&cnt[key * CNTSTRIDE], 1);
    if (pos < BCAP) elist[(size_t)key * BCAP + pos] = ((uint)(dst & 127) << 17) | (uint)src;
}

// ---------- bf16 helpers ----------

__device__ __forceinline__ uint bf16pack(float a, float b) {
    uint ua = __float_as_uint(a);
    ua = (ua + 0x7FFFu + ((ua >> 16) & 1u)) >> 16;  // RNE
    uint ub = __float_as_uint(b);
    ub = (ub + 0x7FFFu + ((ub >> 16) & 1u)) >> 16;
    return ua | (ub << 16);
}
__device__ __forceinline__ float bf_lo(uint u) { return __uint_as_float(u << 16); }
__device__ __forceinline__ float bf_hi(uint u) { return __uint_as_float(u & 0xFFFF0000u); }

// ---------- aggregation: src-tiled, edge-centric, LDS fp32 accumulators ----------
// Block b owns dst rows [b*128, b*128+128) in a 64KB LDS accumulator and walks
// its 13 sub-buckets in src-tile order: all gathers land in a 2MB window that
// fits per-XCD L2, and all resident blocks sweep tiles near-lockstep.
// h' = p + agg(p) + bias; p bf16-packed (128 dims = 64 uints = 256B row).
// Acc layout is DE-INTERLEAVED: row r = [lo dims (2l) at c=l | hi dims (2l+1)
// at c=64+l] so each LDS atomic hits bank lane%32 (2-way alias = free, G4).

__global__ __launch_bounds__(256) void agg128_tiled(const uint* __restrict__ p,
                                                    const int* __restrict__ cnt,
                                                    const uint* __restrict__ elist,
                                                    const float* __restrict__ bias,
                                                    uint* __restrict__ out) {
    __shared__ float acc[128 * 128];  // 64 KB
    int tid = threadIdx.x;
    int b = blockIdx.x;
    int m0 = b * 128;
    int lane = tid & 63;
    int w = tid >> 6;
#pragma unroll
    for (int i = 0; i < 16; ++i) ((float4*)acc)[tid + i * 256] = (float4){0.f, 0.f, 0.f, 0.f};
    __syncthreads();

    for (int t = 0; t < NT; ++t) {
        int kbase = b * NT + t;
        int n = cnt[kbase * CNTSTRIDE];
        if (n > BCAP) n = BCAP;
        const uint* el = elist + (size_t)kbase * BCAP;
        int e = w;  // wave-per-edge, 4 waves strided
        for (; e + 28 < n; e += 32) {  // unroll 8: 8 gathers in flight/wave
            uint k[8], u[8];
#pragma unroll
            for (int j = 0; j < 8; ++j) k[j] = el[e + 4 * j];
#pragma unroll
            for (int j = 0; j < 8; ++j) u[j] = p[(size_t)(k[j] & 0x1FFFF) * 64 + lane];
#pragma unroll
            for (int j = 0; j < 8; ++j) {
                int dl = k[j] >> 17;
                atomicAdd(&acc[dl * 128 + lane], bf_lo(u[j]));
                atomicAdd(&acc[dl * 128 + 64 + lane], bf_hi(u[j]));
            }
        }
        for (; e < n; e += 4) {
            uint k = el[e];
            uint u = p[(size_t)(k & 0x1FFFF) * 64 + lane];
            int dl = k >> 17;
            atomicAdd(&acc[dl * 128 + lane], bf_lo(u));
            atomicAdd(&acc[dl * 128 + 64 + lane], bf_hi(u));
        }
    }
    __syncthreads();
    // writeback: out[v] = p[v] + acc[v] + bias (bf16-packed, nontemporal)
    // 128 rows x 64 uint-cols = 8192 items = 32 iters.
#pragma unroll
    for (int i = 0; i < 32; ++i) {
        int idx = tid + i * 256;
        int r = idx >> 6, c = idx & 63;
        int v = m0 + r;
        if (v < N_NODES) {
            uint self = p[(size_t)v * 64 + c];
            float ox = acc[r * 128 + c] + bf_lo(self) + bias[2 * c];
            float oy = acc[r * 128 + 64 + c] + bf_hi(self) + bias[2 * c + 1];
            __builtin_nontemporal_store(bf16pack(ox, oy), &out[(size_t)v * 64 + c]);
        }
    }
}

// 64-dim variant (layer 4): p rows = 32 uints (128B); each wave processes 2
// edges at once (half-wave each). Output fp32 to d_out.
// Acc row r = [lo dims at c=l32 | hi dims at c=32+l32].
__global__ __launch_bounds__(256) void agg64_tiled(const uint* __restrict__ p,
                                                   const int* __restrict__ cnt,
                                                   const uint* __restrict__ elist,
                                                   const float* __restrict__ bias,
                                                   float* __restrict__ out) {
    __shared__ float acc[128 * 64];  // 32 KB
    int tid = threadIdx.x;
    int b = blockIdx.x;
    int m0 = b * 128;
    int lane = tid & 63;
    int w = tid >> 6;
    int half = lane >> 5, l32 = lane & 31;
#pragma unroll
    for (int i = 0; i < 8; ++i) ((float4*)acc)[tid + i * 256] = (float4){0.f, 0.f, 0.f, 0.f};
    __syncthreads();

    for (int t = 0; t < NT; ++t) {
        int kbase = b * NT + t;
        int n = cnt[kbase * CNTSTRIDE];
        if (n > BCAP) n = BCAP;
        const uint* el = elist + (size_t)kbase * BCAP;
        for (int e2 = 2 * w; e2 < n; e2 += 32) {  // 4 waves x 2 edges, unroll 4
#pragma unroll
            for (int j = 0; j < 4; ++j) {
                int ee = e2 + 8 * j + half;
                if (ee < n) {
                    uint k = el[ee];
                    uint u = p[(size_t)(k & 0x1FFFF) * 32 + l32];
                    int dl = k >> 17;
                    atomicAdd(&acc[dl * 64 + l32], bf_lo(u));
                    atomicAdd(&acc[dl * 64 + 32 + l32], bf_hi(u));
                }
            }
        }
    }
    __syncthreads();
    // writeback: 128 rows x 32 uint-cols = 4096 items = 16 iters. (R7 bug: was 32.)
#pragma unroll
    for (int i = 0; i < 16; ++i) {
        int idx = tid + i * 256;
        int r = idx >> 5, c = idx & 31;
        int v = m0 + r;
        if (v < N_NODES) {
            uint self = p[(size_t)v * 32 + c];
            float ox = acc[r * 64 + c] + bf_lo(self) + bias[2 * c];
            float oy = acc[r * 64 + 32 + c] + bf_hi(self) + bias[2 * c + 1];
            __builtin_nontemporal_store(ox, &out[(size_t)v * 64 + 2 * c]);
            __builtin_nontemporal_store(oy, &out[(size_t)v * 64 + 2 * c + 1]);
        }
    }
}

// ---------- MFMA GEMM ----------
// prep_w: W (fp32 [128][NOUT]) -> Wt bf16, [n][c16] uint4 units (c16 = 8-k
// chunk), XOR-swizzled (c16 ^= n&7) to kill 16-way LDS bank conflicts (G4).

template <int NOUT>
__global__ __launch_bounds__(256) void prep_w(const float* __restrict__ W,
                                              u4v* __restrict__ Wt) {
    int idx = blockIdx.x * 256 + threadIdx.x;  // n*16 + c16
    if (idx >= NOUT * 16) return;
    int n = idx >> 4, c16 = idx & 15;
    u4v o;
#pragma unroll
    for (int q = 0; q < 4; ++q)
        o[q] = bf16pack(W[(size_t)(c16 * 8 + 2 * q) * NOUT + n],
                        W[(size_t)(c16 * 8 + 2 * q + 1) * NOUT + n]);
    Wt[n * 16 + (c16 ^ (n & 7))] = o;
}

// y[M x NOUT] (bf16-packed) = x[M x 128] @ W. Block: 128 rows, 4 waves.
template <int NOUT, bool A_BF16>
__global__ __launch_bounds__(256) void mfma_gemm(const void* __restrict__ xv,
                                                 const u4v* __restrict__ Wt,
                                                 uint* __restrict__ y) {
    constexpr int STAGE = 32768 + NOUT * 256;        // A (32K) + B
    constexpr int EPIL = 128 * NOUT * 4;             // fp32 C tile
    constexpr int SMEM = STAGE > EPIL ? STAGE : EPIL;
    __shared__ char raw[SMEM];
    u4v* Asm = (u4v*)raw;                  // [128][16] swizzled
    u4v* Bsm = (u4v*)(raw + 32768);        // [NOUT][16] swizzled
    float* Cst = (float*)raw;              // [128][NOUT] epilogue overlay
    int tid = threadIdx.x;
    int m0 = blockIdx.x * 128;

    if constexpr (A_BF16) {
        const u4v* xp = (const u4v*)xv;
#pragma unroll
        for (int i = 0; i < 8; ++i) {
            int idx = tid + i * 256;
            int r = idx >> 4, c16 = idx & 15;
            int m = m0 + r;
            if (m >= N_NODES) m = N_NODES - 1;
            Asm[r * 16 + (c16 ^ (r & 7))] = xp[(size_t)m * 16 + c16];
        }
    } else {
        const float* x = (const float*)xv;
#pragma unroll
        for (int i = 0; i < 8; ++i) {
            int idx = tid + i * 256;
            int r = idx >> 4, c16 = idx & 15;
            int m = m0 + r;
            if (m >= N_NODES) m = N_NODES - 1;
            const float* src = &x[(size_t)m * 128 + c16 * 8];
            float4 v0 = *(const float4*)src;
            float4 v1 = *(const float4*)(src + 4);
            u4v o = {bf16pack(v0.x, v0.y), bf16pack(v0.z, v0.w),
                     bf16pack(v1.x, v1.y), bf16pack(v1.z, v1.w)};
            Asm[r * 16 + (c16 ^ (r & 7))] = o;
        }
    }
#pragma unroll
    for (int i = 0; i < NOUT * 16 / 256; ++i) Bsm[tid + i * 256] = Wt[tid + i * 256];
    __syncthreads();

    constexpr int NF = NOUT / 64;  // n-frags per wave (2 for 128, 1 for 64)
    int lane = tid & 63;
    int w = tid >> 6;
    int n0w = w * (NOUT / 4);
    int lhi = lane >> 4, llo = lane & 15;
    f32x4 acc[8][NF];
#pragma unroll
    for (int i = 0; i < 8; ++i)
#pragma unroll
        for (int j = 0; j < NF; ++j) acc[i][j] = (f32x4){0.f, 0.f, 0.f, 0.f};

#pragma unroll
    for (int ks = 0; ks < 4; ++ks) {
        int cb = ks * 4 + lhi;
        s8v bfr[NF];
#pragma unroll
        for (int j = 0; j < NF; ++j) {
            int col = n0w + j * 16 + llo;
            u4v t = Bsm[col * 16 + (cb ^ (col & 7))];
            bfr[j] = *(s8v*)&t;
        }
#pragma unroll
        for (int i = 0; i < 8; ++i) {
            int row = i * 16 + llo;
            u4v t = Asm[row * 16 + (cb ^ (row & 7))];
            s8v a = *(s8v*)&t;
#pragma unroll
            for (int j = 0; j < NF; ++j)
                acc[i][j] = __builtin_amdgcn_mfma_f32_16x16x32_bf16(a, bfr[j], acc[i][j], 0, 0, 0);
        }
    }
    __syncthreads();
#pragma unroll
    for (int i = 0; i < 8; ++i)
#pragma unroll
        for (int j = 0; j < NF; ++j)
#pragma unroll
            for (int r = 0; r < 4; ++r)
                Cst[(i * 16 + lhi * 4 + r) * NOUT + n0w + j * 16 + llo] = acc[i][j][r];
    __syncthreads();
#pragma unroll
    for (int i = 0; i < 128 * NOUT / 2 / 256; ++i) {
        int idx = tid + i * 256;
        int m = idx / (NOUT / 2), np = idx % (NOUT / 2);
        if (m0 + m < N_NODES)
            y[(size_t)(m0 + m) * (NOUT / 2) + np] =
                bf16pack(Cst[m * NOUT + 2 * np], Cst[m * NOUT + 2 * np + 1]);
    }
}

extern "C" void kernel_launch(void* const* d_in, const int* in_sizes, int n_in,
                              void* d_out, int out_size, void* d_ws, size_t ws_size,
                              hipStream_t stream) {
    const float* h_in = (const float*)d_in[0];
    const void* edges = d_in[1];
    const float* W[5] = {(const float*)d_in[2], (const float*)d_in[4], (const float*)d_in[6],
                         (const float*)d_in[8], (const float*)d_in[10]};
    const float* B[5] = {(const float*)d_in[3], (const float*)d_in[5], (const float*)d_in[7],
                         (const float*)d_in[9], (const float*)d_in[11]};

    size_t off = 0;
    auto alloc = [&](size_t bytes) {
        void* p = (char*)d_ws + off;
        off = (off + bytes + 255) & ~(size_t)255;
        return p;
    };
    int* cnt = (int*)alloc((size_t)NKEY * CNTSTRIDE * 4);   // 650 KB (padded cursors)
    uint* elist = (uint*)alloc((size_t)NKEY * BCAP * 4);    // 26.0 MB
    int* flag = (int*)alloc(256);
    u4v* Wt[5];
    for (int l = 0; l < 5; ++l) Wt[l] = (u4v*)alloc((size_t)128 * 16 * 16);
    uint* C = (uint*)alloc((size_t)N_NODES * 64 * 4);       // 25.6 MB (p, bf16)
    uint* D = (uint*)alloc((size_t)N_NODES * 64 * 4);       // 25.6 MB (h', bf16)

    // ---- build partitioned edge list ----
    detect_fmt<<<1, 64, 0, stream>>>((const uint*)edges, flag);
    hipMemsetAsync(cnt, 0, (size_t)NKEY * CNTSTRIDE * 4, stream);
    scatter_direct<<<(N_EDGES + 255) / 256, 256, 0, stream>>>(edges, flag, cnt, elist);

    // ---- weight prep (bf16 transpose + swizzle) ----
    for (int l = 0; l < 4; ++l) prep_w<128><<<8, 256, 0, stream>>>(W[l], Wt[l]);
    prep_w<64><<<4, 256, 0, stream>>>(W[4], Wt[4]);

    // ---- 5 GIN layers: p = h @ W (MFMA, bf16); h' = p + agg(p) + b ----
    mfma_gemm<128, false><<<NDB, 256, 0, stream>>>(h_in, Wt[0], C);
    agg128_tiled<<<NDB, 256, 0, stream>>>(C, cnt, elist, B[0], D);
    for (int l = 1; l <= 3; ++l) {
        mfma_gemm<128, true><<<NDB, 256, 0, stream>>>(D, Wt[l], C);
        agg128_tiled<<<NDB, 256, 0, stream>>>(C, cnt, elist, B[l], D);
    }
    mfma_gemm<64, true><<<NDB, 256, 0, stream>>>(D, Wt[4], C);
    agg64_tiled<<<NDB, 256, 0, stream>>>(C, cnt, elist, B[4], (float*)d_out);
}

// Round 9
// 708.931 us; speedup vs baseline: 17.3146x; 17.3146x over previous
//
#include <hip/hip_runtime.h>

#define N_NODES 100000
#define N_EDGES 3200000
#define NB 782          // dst buckets of 128 nodes: ceil(100000/128)
#define BCAP 5120       // max edges per bucket (avg 4096, 16 sigma guard)
#define CHUNK_EDGES 16384
#define NCHUNKS ((N_EDGES + CHUNK_EDGES - 1) / CHUNK_EDGES)  // 196

typedef unsigned int uint;
typedef __attribute__((ext_vector_type(2))) uint u2v;
typedef __attribute__((ext_vector_type(4))) uint u4v;
typedef __attribute__((ext_vector_type(2))) float f2v;
typedef __attribute__((ext_vector_type(8))) short s8v;   // 8 bf16 (4 VGPRs)
typedef __attribute__((ext_vector_type(4))) float f32x4; // mfma acc

// ---------- CSR build: deterministic two-pass bucket partition (R6, proven) ----------

__global__ void detect_fmt(const uint* __restrict__ e, int* __restrict__ flag,
                           int* __restrict__ row_ptr) {
    if (threadIdx.x == 0) {
        *flag = (e[1] == 0u && e[3] == 0u && e[5] == 0u && e[7] == 0u) ? 1 : 0;
        row_ptr[N_NODES] = N_EDGES;
    }
}

__device__ __forceinline__ int load_idx(const void* edges, int fmt, long long i) {
    return fmt ? (int)((const long long*)edges)[i] : ((const int*)edges)[i];
}

__global__ __launch_bounds__(256) void part_hist(const void* __restrict__ edges,
                                                 const int* __restrict__ flag,
                                                 int* __restrict__ hist2,
                                                 int* __restrict__ bcount) {
    __shared__ int cnt[NB];
    for (int i = threadIdx.x; i < NB; i += 256) cnt[i] = 0;
    __syncthreads();
    int fmt = *flag;
    int c = blockIdx.x;
    int beg = c * CHUNK_EDGES, end = min(beg + CHUNK_EDGES, N_EDGES);
    for (int i = beg + threadIdx.x; i < end; i += 256) {
        int dst = load_idx(edges, fmt, (long long)N_EDGES + i);
        atomicAdd(&cnt[dst >> 7], 1);
    }
    __syncthreads();
    for (int i = threadIdx.x; i < NB; i += 256) {
        hist2[c * NB + i] = cnt[i];
        if (cnt[i]) atomicAdd(&bcount[i], cnt[i]);
    }
}

__global__ void scan_kernel(const int* __restrict__ count, int* __restrict__ off_out, int n) {
    __shared__ int sums[1024];
    int t = threadIdx.x;
    int chunk = (n + 1023) >> 10;
    int beg = t * chunk;
    int end = min(beg + chunk, n);
    int s = 0;
    for (int i = beg; i < end; ++i) s += count[i];
    sums[t] = s;
    __syncthreads();
    int val = s;
    for (int off = 1; off < 1024; off <<= 1) {
        int other = (t >= off) ? sums[t - off] : 0;
        __syncthreads();
        val += other;
        sums[t] = val;
        __syncthreads();
    }
    int run = val - s;
    for (int i = beg; i < end; ++i) {
        off_out[i] = run;
        run += count[i];
    }
    if (end >= n) off_out[n] = run;
}

__global__ __launch_bounds__(256) void chunk_scan(const int* __restrict__ hist2,
                                                  const int* __restrict__ boff,
                                                  int* __restrict__ base2) {
    __shared__ int s[256];
    int b = blockIdx.x;
    int t = threadIdx.x;
    int v = (t < NCHUNKS) ? hist2[t * NB + b] : 0;
    s[t] = v;
    __syncthreads();
    int val = v;
    for (int off = 1; off < 256; off <<= 1) {
        int o = (t >= off) ? s[t - off] : 0;
        __syncthreads();
        val += o;
        s[t] = val;
        __syncthreads();
    }
    if (t < NCHUNKS) base2[t * NB + b] = boff[b] + val - v;
}

__global__ __launch_bounds__(256) void part_scatter(const void* __restrict__ edges,
                                                    const int* __restrict__ flag,
                                                    const int* __restrict__ base2,
                                                    uint* __restrict__ tmp) {
    __shared__ int cur[NB];
    int c = blockIdx.x;
    for (int i = threadIdx.x; i < NB; i += 256) cur[i] = base2[c * NB + i];
    __syncthreads();
    int fmt = *flag;
    int beg = c * CHUNK_EDGES, end = min(beg + CHUNK_EDGES, N_EDGES);
    for (int i = beg + threadIdx.x; i < end; i += 256) {
        int src = load_idx(edges, fmt, i);
        int dst = load_idx(edges, fmt, (long long)N_EDGES + i);
        int b = dst >> 7;
        int pos = atomicAdd(&cur[b], 1);
        tmp[pos] = ((uint)(dst & 127) << 17) | (uint)src;  // src < 2^17
    }
}

__global__ __launch_bounds__(256) void bucket_finalize(const uint* __restrict__ tmp,
                                                       const int* __restrict__ boff,
                                                       int* __restrict__ row_ptr,
                                                       int* __restrict__ esorted) {
    __shared__ uint s1[BCAP];
    __shared__ int s2[BCAP];
    __shared__ int cnt[128], pref[128], cur[128];
    int b = blockIdx.x;
    int beg = boff[b];
    int n = boff[b + 1] - beg;
    if (n > BCAP) n = BCAP;
    int t = threadIdx.x;
    if (t < 128) cnt[t] = 0;
    __syncthreads();
    for (int e = t; e < n; e += 256) {
        uint k = tmp[beg + e];
        s1[e] = k;
        atomicAdd(&cnt[k >> 17], 1);
    }
    __syncthreads();
    if (t < 128) pref[t] = cnt[t];
    __syncthreads();
    for (int off = 1; off < 128; off <<= 1) {
        int v = (t < 128 && t >= off) ? pref[t - off] : 0;
        __syncthreads();
        if (t < 128) pref[t] += v;
        __syncthreads();
    }
    if (t < 128) {
        int ex = pref[t] - cnt[t];
        cur[t] = ex;
        int node = b * 128 + t;
        if (node < N_NODES) row_ptr[node] = beg + ex;
    }
    __syncthreads();
    for (int e = t; e < n; e += 256) {
        uint k = s1[e];
        int p = atomicAdd(&cur[k >> 17], 1);
        s2[p] = (int)(k & 0x1FFFF);
    }
    __syncthreads();
    for (int e = t; e < n; e += 256) esorted[beg + e] = s2[e];
}

// ---------- bf16 helpers ----------

__device__ __forceinline__ uint bf16pack(float a, float b) {
    uint ua = __float_as_uint(a);
    ua = (ua + 0x7FFFu + ((ua >> 16) & 1u)) >> 16;  // RNE
    uint ub = __float_as_uint(b);
    ub = (ub + 0x7FFFu + ((ub >> 16) & 1u)) >> 16;
    return ua | (ub << 16);
}
__device__ __forceinline__ float bf_lo(uint u) { return __uint_as_float(u << 16); }
__device__ __forceinline__ float bf_hi(uint u) { return __uint_as_float(u & 0xFFFF0000u); }

// ---------- aggregation (R6 streaming pattern, 2 edges/wave-instr) ----------
// h' = p + agg(p) + bias; p bf16-packed. Lanes 0-31 accumulate even edges,
// 32-63 odd: each lane gathers uint2 (8B) so one global_load_dwordx2 = 512B =
// two full 256B rows. Halves combined by shfl_xor(32) at node end. Addresses
// kept in 32-bit (SGPR base + voffset). float2 accs -> v_pk_add_f32.

__global__ __launch_bounds__(256) void agg128(const uint* __restrict__ p,
                                              const int* __restrict__ row_ptr,
                                              const int* __restrict__ esrc,
                                              const float* __restrict__ bias,
                                              uint* __restrict__ out) {
    const u2v* p2 = (const u2v*)p;
    int lane = threadIdx.x & 63;
    int l32 = lane & 31;
    int half = lane >> 5;
    int wid = (blockIdx.x * blockDim.x + threadIdx.x) >> 6;
    int nw = (gridDim.x * blockDim.x) >> 6;
    float4 bv = ((const float4*)bias)[l32];  // dims 4*l32 .. 4*l32+3
    for (int v = wid; v < N_NODES; v += nw) {
        f2v a01 = {0.f, 0.f}, a23 = {0.f, 0.f};
        int beg = row_ptr[v], end = row_ptr[v + 1];
        int i = beg;
        for (; i + 8 <= end; i += 8) {  // 4 pairs = 8 edges, 4 gathers in flight
            uint k[4];
            u2v u[4];
#pragma unroll
            for (int j = 0; j < 4; ++j) k[j] = (uint)esrc[i + 2 * j + half];
#pragma unroll
            for (int j = 0; j < 4; ++j) u[j] = p2[k[j] * 32u + (uint)l32];
#pragma unroll
            for (int j = 0; j < 4; ++j) {
                f2v t0 = {bf_lo(u[j].x), bf_hi(u[j].x)};
                f2v t1 = {bf_lo(u[j].y), bf_hi(u[j].y)};
                a01 += t0;
                a23 += t1;
            }
        }
        for (; i < end; i += 2) {  // tail pairs (and possible odd edge)
            int idx = i + half;
            u2v uu = {0u, 0u};
            if (idx < end) uu = p2[(uint)esrc[idx] * 32u + (uint)l32];
            f2v t0 = {bf_lo(uu.x), bf_hi(uu.x)};
            f2v t1 = {bf_lo(uu.y), bf_hi(uu.y)};
            a01 += t0;
            a23 += t1;
        }
        a01.x += __shfl_xor(a01.x, 32);
        a01.y += __shfl_xor(a01.y, 32);
        a23.x += __shfl_xor(a23.x, 32);
        a23.y += __shfl_xor(a23.y, 32);
        if (half == 0) {
            u2v self = p2[(uint)v * 32u + (uint)l32];
            float d0 = a01.x + bf_lo(self.x) + bv.x;
            float d1 = a01.y + bf_hi(self.x) + bv.y;
            float d2 = a23.x + bf_lo(self.y) + bv.z;
            float d3 = a23.y + bf_hi(self.y) + bv.w;
            u2v o = {bf16pack(d0, d1), bf16pack(d2, d3)};
            __builtin_nontemporal_store(o, &((u2v*)out)[(uint)v * 32u + (uint)l32]);
        }
    }
}

// 64-dim variant (layer 4): rows = 32 uints (128B); lane loads uint -> one
// global_load_dword = 256B = two rows. Output fp32 to d_out.
__global__ __launch_bounds__(256) void agg64(const uint* __restrict__ p,
                                             const int* __restrict__ row_ptr,
                                             const int* __restrict__ esrc,
                                             const float* __restrict__ bias,
                                             float* __restrict__ out) {
    int lane = threadIdx.x & 63;
    int l32 = lane & 31;
    int half = lane >> 5;
    int wid = (blockIdx.x * blockDim.x + threadIdx.x) >> 6;
    int nw = (gridDim.x * blockDim.x) >> 6;
    f2v bv = ((const f2v*)bias)[l32];  // dims 2*l32, 2*l32+1
    for (int v = wid; v < N_NODES; v += nw) {
        f2v a = {0.f, 0.f};
        int beg = row_ptr[v], end = row_ptr[v + 1];
        int i = beg;
        for (; i + 16 <= end; i += 16) {  // 8 pairs = 16 edges, 8 gathers in flight
            uint k[8], u[8];
#pragma unroll
            for (int j = 0; j < 8; ++j) k[j] = (uint)esrc[i + 2 * j + half];
#pragma unroll
            for (int j = 0; j < 8; ++j) u[j] = p[k[j] * 32u + (uint)l32];
#pragma unroll
            for (int j = 0; j < 8; ++j) {
                f2v t = {bf_lo(u[j]), bf_hi(u[j])};
                a += t;
            }
        }
        for (; i < end; i += 2) {
            int idx = i + half;
            uint uu = 0u;
            if (idx < end) uu = p[(uint)esrc[idx] * 32u + (uint)l32];
            f2v t = {bf_lo(uu), bf_hi(uu)};
            a += t;
        }
        a.x += __shfl_xor(a.x, 32);
        a.y += __shfl_xor(a.y, 32);
        if (half == 0) {
            uint self = p[(uint)v * 32u + (uint)l32];
            f2v o = {a.x + bf_lo(self) + bv.x, a.y + bf_hi(self) + bv.y};
            __builtin_nontemporal_store(o, &((f2v*)out)[(uint)v * 32u + (uint)l32]);
        }
    }
}

// ---------- MFMA GEMM (R6, proven) ----------

template <int NOUT>
__global__ __launch_bounds__(256) void prep_w(const float* __restrict__ W,
                                              u4v* __restrict__ Wt) {
    int idx = blockIdx.x * 256 + threadIdx.x;  // n*16 + c16
    if (idx >= NOUT * 16) return;
    int n = idx >> 4, c16 = idx & 15;
    u4v o;
#pragma unroll
    for (int q = 0; q < 4; ++q)
        o[q] = bf16pack(W[(size_t)(c16 * 8 + 2 * q) * NOUT + n],
                        W[(size_t)(c16 * 8 + 2 * q + 1) * NOUT + n]);
    Wt[n * 16 + (c16 ^ (n & 7))] = o;
}

template <int NOUT, bool A_BF16>
__global__ __launch_bounds__(256) void mfma_gemm(const void* __restrict__ xv,
                                                 const u4v* __restrict__ Wt,
                                                 uint* __restrict__ y) {
    constexpr int STAGE = 32768 + NOUT * 256;        // A (32K) + B
    constexpr int EPIL = 128 * NOUT * 4;             // fp32 C tile
    constexpr int SMEM = STAGE > EPIL ? STAGE : EPIL;
    __shared__ char raw[SMEM];
    u4v* Asm = (u4v*)raw;                  // [128][16] swizzled
    u4v* Bsm = (u4v*)(raw + 32768);        // [NOUT][16] swizzled
    float* Cst = (float*)raw;              // [128][NOUT] epilogue overlay
    int tid = threadIdx.x;
    int m0 = blockIdx.x * 128;

    if constexpr (A_BF16) {
        const u4v* xp = (const u4v*)xv;
#pragma unroll
        for (int i = 0; i < 8; ++i) {
            int idx = tid + i * 256;
            int r = idx >> 4, c16 = idx & 15;
            int m = m0 + r;
            if (m >= N_NODES) m = N_NODES - 1;
            Asm[r * 16 + (c16 ^ (r & 7))] = xp[(size_t)m * 16 + c16];
        }
    } else {
        const float* x = (const float*)xv;
#pragma unroll
        for (int i = 0; i < 8; ++i) {
            int idx = tid + i * 256;
            int r = idx >> 4, c16 = idx & 15;
            int m = m0 + r;
            if (m >= N_NODES) m = N_NODES - 1;
            const float* src = &x[(size_t)m * 128 + c16 * 8];
            float4 v0 = *(const float4*)src;
            float4 v1 = *(const float4*)(src + 4);
            u4v o = {bf16pack(v0.x, v0.y), bf16pack(v0.z, v0.w),
                     bf16pack(v1.x, v1.y), bf16pack(v1.z, v1.w)};
            Asm[r * 16 + (c16 ^ (r & 7))] = o;
        }
    }
#pragma unroll
    for (int i = 0; i < NOUT * 16 / 256; ++i) Bsm[tid + i * 256] = Wt[tid + i * 256];
    __syncthreads();

    constexpr int NF = NOUT / 64;  // n-frags per wave (2 for 128, 1 for 64)
    int lane = tid & 63;
    int w = tid >> 6;
    int n0w = w * (NOUT / 4);
    int lhi = lane >> 4, llo = lane & 15;
    f32x4 acc[8][NF];
#pragma unroll
    for (int i = 0; i < 8; ++i)
#pragma unroll
        for (int j = 0; j < NF; ++j) acc[i][j] = (f32x4){0.f, 0.f, 0.f, 0.f};

#pragma unroll
    for (int ks = 0; ks < 4; ++ks) {
        int cb = ks * 4 + lhi;
        s8v bfr[NF];
#pragma unroll
        for (int j = 0; j < NF; ++j) {
            int col = n0w + j * 16 + llo;
            u4v t = Bsm[col * 16 + (cb ^ (col & 7))];
            bfr[j] = *(s8v*)&t;
        }
#pragma unroll
        for (int i = 0; i < 8; ++i) {
            int row = i * 16 + llo;
            u4v t = Asm[row * 16 + (cb ^ (row & 7))];
            s8v a = *(s8v*)&t;
#pragma unroll
            for (int j = 0; j < NF; ++j)
                acc[i][j] = __builtin_amdgcn_mfma_f32_16x16x32_bf16(a, bfr[j], acc[i][j], 0, 0, 0);
        }
    }
    __syncthreads();
#pragma unroll
    for (int i = 0; i < 8; ++i)
#pragma unroll
        for (int j = 0; j < NF; ++j)
#pragma unroll
            for (int r = 0; r < 4; ++r)
                Cst[(i * 16 + lhi * 4 + r) * NOUT + n0w + j * 16 + llo] = acc[i][j][r];
    __syncthreads();
#pragma unroll
    for (int i = 0; i < 128 * NOUT / 2 / 256; ++i) {
        int idx = tid + i * 256;
        int m = idx / (NOUT / 2), np = idx % (NOUT / 2);
        if (m0 + m < N_NODES)
            y[(size_t)(m0 + m) * (NOUT / 2) + np] =
                bf16pack(Cst[m * NOUT + 2 * np], Cst[m * NOUT + 2 * np + 1]);
    }
}

extern "C" void kernel_launch(void* const* d_in, const int* in_sizes, int n_in,
                              void* d_out, int out_size, void* d_ws, size_t ws_size,
                              hipStream_t stream) {
    const float* h_in = (const float*)d_in[0];
    const void* edges = d_in[1];
    const float* W[5] = {(const float*)d_in[2], (const float*)d_in[4], (const float*)d_in[6],
                         (const float*)d_in[8], (const float*)d_in[10]};
    const float* B[5] = {(const float*)d_in[3], (const float*)d_in[5], (const float*)d_in[7],
                         (const float*)d_in[9], (const float*)d_in[11]};

    size_t off = 0;
    auto alloc = [&](size_t bytes) {
        void* p = (char*)d_ws + off;
        off = (off + bytes + 255) & ~(size_t)255;
        return p;
    };
    int* esorted = (int*)alloc((size_t)N_EDGES * 4);            // 12.8 MB
    int* row_ptr = (int*)alloc((size_t)(N_NODES + 1) * 4);
    int* hist2 = (int*)alloc((size_t)NCHUNKS * NB * 4);
    int* base2 = (int*)alloc((size_t)NCHUNKS * NB * 4);
    int* bcount = (int*)alloc((size_t)NB * 4);
    int* boff = (int*)alloc((size_t)(NB + 1) * 4);
    int* flag = (int*)alloc(256);
    u4v* Wt[5];
    for (int l = 0; l < 5; ++l) Wt[l] = (u4v*)alloc((size_t)128 * 16 * 16);
    uint* C = (uint*)alloc((size_t)N_NODES * 64 * 4);           // 25.6 MB (p, bf16)
    uint* D = (uint*)alloc((size_t)N_NODES * 64 * 4);           // 25.6 MB (h', bf16)
    uint* tmp = (uint*)alloc((size_t)N_EDGES * 4);              // 12.8 MB (build only)

    // ---- build CSR ----
    detect_fmt<<<1, 64, 0, stream>>>((const uint*)edges, flag, row_ptr);
    hipMemsetAsync(bcount, 0, (size_t)NB * 4, stream);
    part_hist<<<NCHUNKS, 256, 0, stream>>>(edges, flag, hist2, bcount);
    scan_kernel<<<1, 1024, 0, stream>>>(bcount, boff, NB);
    chunk_scan<<<NB, 256, 0, stream>>>(hist2, boff, base2);
    part_scatter<<<NCHUNKS, 256, 0, stream>>>(edges, flag, base2, tmp);
    bucket_finalize<<<NB, 256, 0, stream>>>(tmp, boff, row_ptr, esorted);

    // ---- weight prep (bf16 transpose + swizzle) ----
    for (int l = 0; l < 4; ++l) prep_w<128><<<8, 256, 0, stream>>>(W[l], Wt[l]);
    prep_w<64><<<4, 256, 0, stream>>>(W[4], Wt[4]);

    // ---- 5 GIN layers: p = h @ W (MFMA, bf16); h' = p + agg(p) + b ----
    const int NBLK = (N_NODES + 127) / 128;  // 782

    mfma_gemm<128, false><<<NBLK, 256, 0, stream>>>(h_in, Wt[0], C);
    agg128<<<4096, 256, 0, stream>>>(C, row_ptr, esorted, B[0], D);
    for (int l = 1; l <= 3; ++l) {
        mfma_gemm<128, true><<<NBLK, 256, 0, stream>>>(D, Wt[l], C);
        agg128<<<4096, 256, 0, stream>>>(C, row_ptr, esorted, B[l], D);
    }
    mfma_gemm<64, true><<<NBLK, 256, 0, stream>>>(D, Wt[4], C);
    agg64<<<2048, 256, 0, stream>>>(C, row_ptr, esorted, B[4], (float*)d_out);
}

// Round 11
// 657.086 us; speedup vs baseline: 18.6808x; 1.0789x over previous
//
#include <hip/hip_runtime.h>

#define N_NODES 100000
#define N_EDGES 3200000
#define NB 782          // dst buckets of 128 nodes: ceil(100000/128)
#define BCAP 5120       // max edges per bucket (avg 4096, 16 sigma guard)
#define CHUNK_EDGES 16384
#define NCHUNKS ((N_EDGES + CHUNK_EDGES - 1) / CHUNK_EDGES)  // 196

typedef unsigned int uint;
typedef __attribute__((ext_vector_type(2))) uint u2v;
typedef __attribute__((ext_vector_type(4))) uint u4v;
typedef __attribute__((ext_vector_type(2))) float f2v;
typedef __attribute__((ext_vector_type(8))) short s8v;   // 8 bf16 (4 VGPRs)
typedef __attribute__((ext_vector_type(4))) float f32x4; // mfma acc

// ---------- CSR build: deterministic two-pass bucket partition (R9, proven) ----------

__global__ void detect_fmt(const uint* __restrict__ e, int* __restrict__ flag,
                           int* __restrict__ row_ptr) {
    if (threadIdx.x == 0) {
        *flag = (e[1] == 0u && e[3] == 0u && e[5] == 0u && e[7] == 0u) ? 1 : 0;
        row_ptr[N_NODES] = N_EDGES;
    }
}

__device__ __forceinline__ int load_idx(const void* edges, int fmt, long long i) {
    return fmt ? (int)((const long long*)edges)[i] : ((const int*)edges)[i];
}

__global__ __launch_bounds__(256) void part_hist(const void* __restrict__ edges,
                                                 const int* __restrict__ flag,
                                                 int* __restrict__ hist2,
                                                 int* __restrict__ bcount) {
    __shared__ int cnt[NB];
    for (int i = threadIdx.x; i < NB; i += 256) cnt[i] = 0;
    __syncthreads();
    int fmt = *flag;
    int c = blockIdx.x;
    int beg = c * CHUNK_EDGES, end = min(beg + CHUNK_EDGES, N_EDGES);
    for (int i = beg + threadIdx.x; i < end; i += 256) {
        int dst = load_idx(edges, fmt, (long long)N_EDGES + i);
        atomicAdd(&cnt[dst >> 7], 1);
    }
    __syncthreads();
    for (int i = threadIdx.x; i < NB; i += 256) {
        hist2[c * NB + i] = cnt[i];
        if (cnt[i]) atomicAdd(&bcount[i], cnt[i]);
    }
}

__global__ void scan_kernel(const int* __restrict__ count, int* __restrict__ off_out, int n) {
    __shared__ int sums[1024];
    int t = threadIdx.x;
    int chunk = (n + 1023) >> 10;
    int beg = t * chunk;
    int end = min(beg + chunk, n);
    int s = 0;
    for (int i = beg; i < end; ++i) s += count[i];
    sums[t] = s;
    __syncthreads();
    int val = s;
    for (int off = 1; off < 1024; off <<= 1) {
        int other = (t >= off) ? sums[t - off] : 0;
        __syncthreads();
        val += other;
        sums[t] = val;
        __syncthreads();
    }
    int run = val - s;
    for (int i = beg; i < end; ++i) {
        off_out[i] = run;
        run += count[i];
    }
    if (end >= n) off_out[n] = run;
}

__global__ __launch_bounds__(256) void chunk_scan(const int* __restrict__ hist2,
                                                  const int* __restrict__ boff,
                                                  int* __restrict__ base2) {
    __shared__ int s[256];
    int b = blockIdx.x;
    int t = threadIdx.x;
    int v = (t < NCHUNKS) ? hist2[t * NB + b] : 0;
    s[t] = v;
    __syncthreads();
    int val = v;
    for (int off = 1; off < 256; off <<= 1) {
        int o = (t >= off) ? s[t - off] : 0;
        __syncthreads();
        val += o;
        s[t] = val;
        __syncthreads();
    }
    if (t < NCHUNKS) base2[t * NB + b] = boff[b] + val - v;
}

__global__ __launch_bounds__(256) void part_scatter(const void* __restrict__ edges,
                                                    const int* __restrict__ flag,
                                                    const int* __restrict__ base2,
                                                    uint* __restrict__ tmp) {
    __shared__ int cur[NB];
    int c = blockIdx.x;
    for (int i = threadIdx.x; i < NB; i += 256) cur[i] = base2[c * NB + i];
    __syncthreads();
    int fmt = *flag;
    int beg = c * CHUNK_EDGES, end = min(beg + CHUNK_EDGES, N_EDGES);
    for (int i = beg + threadIdx.x; i < end; i += 256) {
        int src = load_idx(edges, fmt, i);
        int dst = load_idx(edges, fmt, (long long)N_EDGES + i);
        int b = dst >> 7;
        int pos = atomicAdd(&cur[b], 1);
        tmp[pos] = ((uint)(dst & 127) << 17) | (uint)src;  // src < 2^17
    }
}

__global__ __launch_bounds__(256) void bucket_finalize(const uint* __restrict__ tmp,
                                                       const int* __restrict__ boff,
                                                       int* __restrict__ row_ptr,
                                                       int* __restrict__ esorted) {
    __shared__ uint s1[BCAP];
    __shared__ int s2[BCAP];
    __shared__ int cnt[128], pref[128], cur[128];
    int b = blockIdx.x;
    int beg = boff[b];
    int n = boff[b + 1] - beg;
    if (n > BCAP) n = BCAP;
    int t = threadIdx.x;
    if (t < 128) cnt[t] = 0;
    __syncthreads();
    for (int e = t; e < n; e += 256) {
        uint k = tmp[beg + e];
        s1[e] = k;
        atomicAdd(&cnt[k >> 17], 1);
    }
    __syncthreads();
    if (t < 128) pref[t] = cnt[t];
    __syncthreads();
    for (int off = 1; off < 128; off <<= 1) {
        int v = (t < 128 && t >= off) ? pref[t - off] : 0;
        __syncthreads();
        if (t < 128) pref[t] += v;
        __syncthreads();
    }
    if (t < 128) {
        int ex = pref[t] - cnt[t];
        cur[t] = ex;
        int node = b * 128 + t;
        if (node < N_NODES) row_ptr[node] = beg + ex;
    }
    __syncthreads();
    for (int e = t; e < n; e += 256) {
        uint k = s1[e];
        int p = atomicAdd(&cur[k >> 17], 1);
        s2[p] = (int)(k & 0x1FFFF);
    }
    __syncthreads();
    for (int e = t; e < n; e += 256) esorted[beg + e] = s2[e];
}

// ---------- bf16 helpers ----------

__device__ __forceinline__ uint bf16pack(float a, float b) {
    uint ua = __float_as_uint(a);
    ua = (ua + 0x7FFFu + ((ua >> 16) & 1u)) >> 16;  // RNE
    uint ub = __float_as_uint(b);
    ub = (ub + 0x7FFFu + ((ub >> 16) & 1u)) >> 16;
    return ua | (ub << 16);
}
__device__ __forceinline__ float bf_lo(uint u) { return __uint_as_float(u << 16); }
__device__ __forceinline__ float bf_hi(uint u) { return __uint_as_float(u & 0xFFFF0000u); }

// ---------- aggregation (streaming, 2 edges/wave-instr) ----------

__global__ __launch_bounds__(256) void agg128(const uint* __restrict__ p,
                                              const int* __restrict__ row_ptr,
                                              const int* __restrict__ esrc,
                                              const float* __restrict__ bias,
                                              uint* __restrict__ out) {
    const u2v* p2 = (const u2v*)p;
    int lane = threadIdx.x & 63;
    int l32 = lane & 31;
    int half = lane >> 5;
    int wid = (blockIdx.x * blockDim.x + threadIdx.x) >> 6;
    int nw = (gridDim.x * blockDim.x) >> 6;
    float4 bv = ((const float4*)bias)[l32];
    for (int v = wid; v < N_NODES; v += nw) {
        f2v a01 = {0.f, 0.f}, a23 = {0.f, 0.f};
        int beg = row_ptr[v], end = row_ptr[v + 1];
        int i = beg;
        for (; i + 8 <= end; i += 8) {
            uint k[4];
            u2v u[4];
#pragma unroll
            for (int j = 0; j < 4; ++j) k[j] = (uint)esrc[i + 2 * j + half];
#pragma unroll
            for (int j = 0; j < 4; ++j) u[j] = p2[k[j] * 32u + (uint)l32];
#pragma unroll
            for (int j = 0; j < 4; ++j) {
                f2v t0 = {bf_lo(u[j].x), bf_hi(u[j].x)};
                f2v t1 = {bf_lo(u[j].y), bf_hi(u[j].y)};
                a01 += t0;
                a23 += t1;
            }
        }
        for (; i < end; i += 2) {
            int idx = i + half;
            u2v uu = {0u, 0u};
            if (idx < end) uu = p2[(uint)esrc[idx] * 32u + (uint)l32];
            f2v t0 = {bf_lo(uu.x), bf_hi(uu.x)};
            f2v t1 = {bf_lo(uu.y), bf_hi(uu.y)};
            a01 += t0;
            a23 += t1;
        }
        a01.x += __shfl_xor(a01.x, 32);
        a01.y += __shfl_xor(a01.y, 32);
        a23.x += __shfl_xor(a23.x, 32);
        a23.y += __shfl_xor(a23.y, 32);
        if (half == 0) {
            u2v self = p2[(uint)v * 32u + (uint)l32];
            float d0 = a01.x + bf_lo(self.x) + bv.x;
            float d1 = a01.y + bf_hi(self.x) + bv.y;
            float d2 = a23.x + bf_lo(self.y) + bv.z;
            float d3 = a23.y + bf_hi(self.y) + bv.w;
            u2v o = {bf16pack(d0, d1), bf16pack(d2, d3)};
            __builtin_nontemporal_store(o, &((u2v*)out)[(uint)v * 32u + (uint)l32]);
        }
    }
}

// r[v] = sum_{u in in(v)} q[u]  (pure aggregation, 64-dim bf16 -> bf16)
__global__ __launch_bounds__(256) void agg64_mid(const uint* __restrict__ q,
                                                 const int* __restrict__ row_ptr,
                                                 const int* __restrict__ esrc,
                                                 uint* __restrict__ r) {
    int lane = threadIdx.x & 63;
    int l32 = lane & 31;
    int half = lane >> 5;
    int wid = (blockIdx.x * blockDim.x + threadIdx.x) >> 6;
    int nw = (gridDim.x * blockDim.x) >> 6;
    for (int v = wid; v < N_NODES; v += nw) {
        f2v a = {0.f, 0.f};
        int beg = row_ptr[v], end = row_ptr[v + 1];
        int i = beg;
        for (; i + 16 <= end; i += 16) {
            uint k[8], u[8];
#pragma unroll
            for (int j = 0; j < 8; ++j) k[j] = (uint)esrc[i + 2 * j + half];
#pragma unroll
            for (int j = 0; j < 8; ++j) u[j] = q[k[j] * 32u + (uint)l32];
#pragma unroll
            for (int j = 0; j < 8; ++j) {
                f2v t = {bf_lo(u[j]), bf_hi(u[j])};
                a += t;
            }
        }
        for (; i < end; i += 2) {
            int idx = i + half;
            uint uu = 0u;
            if (idx < end) uu = q[(uint)esrc[idx] * 32u + (uint)l32];
            f2v t = {bf_lo(uu), bf_hi(uu)};
            a += t;
        }
        a.x += __shfl_xor(a.x, 32);
        a.y += __shfl_xor(a.y, 32);
        if (half == 0)
            __builtin_nontemporal_store(bf16pack(a.x, a.y), &r[(uint)v * 32u + (uint)l32]);
    }
}

// out[v] = q[v] + 2 r[v] + sum_{u in in(v)} r[u] + (1+deg_v) c3 + b4   (fp32 out)
__global__ __launch_bounds__(256) void agg64_fin(const uint* __restrict__ r,
                                                 const uint* __restrict__ q,
                                                 const int* __restrict__ row_ptr,
                                                 const int* __restrict__ esrc,
                                                 const float* __restrict__ c3,
                                                 const float* __restrict__ b4,
                                                 float* __restrict__ out) {
    int lane = threadIdx.x & 63;
    int l32 = lane & 31;
    int half = lane >> 5;
    int wid = (blockIdx.x * blockDim.x + threadIdx.x) >> 6;
    int nw = (gridDim.x * blockDim.x) >> 6;
    f2v cv = ((const f2v*)c3)[l32];
    f2v bv = ((const f2v*)b4)[l32];
    for (int v = wid; v < N_NODES; v += nw) {
        f2v a = {0.f, 0.f};
        int beg = row_ptr[v], end = row_ptr[v + 1];
        int i = beg;
        for (; i + 16 <= end; i += 16) {
            uint k[8], u[8];
#pragma unroll
            for (int j = 0; j < 8; ++j) k[j] = (uint)esrc[i + 2 * j + half];
#pragma unroll
            for (int j = 0; j < 8; ++j) u[j] = r[k[j] * 32u + (uint)l32];
#pragma unroll
            for (int j = 0; j < 8; ++j) {
                f2v t = {bf_lo(u[j]), bf_hi(u[j])};
                a += t;
            }
        }
        for (; i < end; i += 2) {
            int idx = i + half;
            uint uu = 0u;
            if (idx < end) uu = r[(uint)esrc[idx] * 32u + (uint)l32];
            f2v t = {bf_lo(uu), bf_hi(uu)};
            a += t;
        }
        a.x += __shfl_xor(a.x, 32);
        a.y += __shfl_xor(a.y, 32);
        if (half == 0) {
            uint qv = q[(uint)v * 32u + (uint)l32];
            uint rv = r[(uint)v * 32u + (uint)l32];
            float degp1 = (float)(end - beg) + 1.0f;
            f2v o;
            o.x = bf_lo(qv) + 2.0f * bf_lo(rv) + a.x + degp1 * cv.x + bv.x;
            o.y = bf_hi(qv) + 2.0f * bf_hi(rv) + a.y + degp1 * cv.y + bv.y;
            __builtin_nontemporal_store(o, &((f2v*)out)[(uint)v * 32u + (uint)l32]);
        }
    }
}

// ---------- MFMA GEMM ----------
// prep_all: all 5 weight transposes (fp32 -> bf16, [n][c16] u4v, XOR-swizzled)
// + c3 = b3 @ W4, in one launch. Blocks 0-31: W0-3 (8 each); 32-35: W4; 36: c3.

__device__ __forceinline__ void prep_body(const float* W, u4v* Wt, int idx, int NOUT) {
    int n = idx >> 4, c16 = idx & 15;
    u4v o;
#pragma unroll
    for (int q = 0; q < 4; ++q)
        o[q] = bf16pack(W[(size_t)(c16 * 8 + 2 * q) * NOUT + n],
                        W[(size_t)(c16 * 8 + 2 * q + 1) * NOUT + n]);
    Wt[n * 16 + (c16 ^ (n & 7))] = o;
}

__global__ __launch_bounds__(256) void prep_all(const float* __restrict__ W0,
                                                const float* __restrict__ W1,
                                                const float* __restrict__ W2,
                                                const float* __restrict__ W3,
                                                const float* __restrict__ W4,
                                                const float* __restrict__ b3,
                                                u4v* __restrict__ Wt0, u4v* __restrict__ Wt1,
                                                u4v* __restrict__ Wt2, u4v* __restrict__ Wt3,
                                                u4v* __restrict__ Wt4,
                                                float* __restrict__ c3) {
    int bid = blockIdx.x;
    int tid = threadIdx.x;
    if (bid < 32) {
        const float* W = (bid < 8) ? W0 : (bid < 16) ? W1 : (bid < 24) ? W2 : W3;
        u4v* Wt = (bid < 8) ? Wt0 : (bid < 16) ? Wt1 : (bid < 24) ? Wt2 : Wt3;
        prep_body(W, Wt, (bid & 7) * 256 + tid, 128);
    } else if (bid < 36) {
        int idx = (bid - 32) * 256 + tid;
        if (idx < 64 * 16) prep_body(W4, Wt4, idx, 64);
    } else {
        if (tid < 64) {
            float s = 0.f;
            for (int k = 0; k < 128; ++k) s += b3[k] * W4[k * 64 + tid];
            c3[tid] = s;
        }
    }
}

template <int NOUT, bool A_BF16>
__global__ __launch_bounds__(256) void mfma_gemm(const void* __restrict__ xv,
                                                 const u4v* __restrict__ Wt,
                                                 uint* __restrict__ y) {
    constexpr int STAGE = 32768 + NOUT * 256;        // A (32K) + B
    constexpr int EPIL = 128 * NOUT * 4;             // fp32 C tile
    constexpr int SMEM = STAGE > EPIL ? STAGE : EPIL;
    __shared__ char raw[SMEM];
    u4v* Asm = (u4v*)raw;                  // [128][16] swizzled
    u4v* Bsm = (u4v*)(raw + 32768);        // [NOUT][16] swizzled
    float* Cst = (float*)raw;              // [128][NOUT] epilogue overlay
    int tid = threadIdx.x;
    int m0 = blockIdx.x * 128;

    if constexpr (A_BF16) {
        const u4v* xp = (const u4v*)xv;
#pragma unroll
        for (int i = 0; i < 8; ++i) {
            int idx = tid + i * 256;
            int r = idx >> 4, c16 = idx & 15;
            int m = m0 + r;
            if (m >= N_NODES) m = N_NODES - 1;
            Asm[r * 16 + (c16 ^ (r & 7))] = xp[(size_t)m * 16 + c16];
        }
    } else {
        const float* x = (const float*)xv;
#pragma unroll
        for (int i = 0; i < 8; ++i) {
            int idx = tid + i * 256;
            int r = idx >> 4, c16 = idx & 15;
            int m = m0 + r;
            if (m >= N_NODES) m = N_NODES - 1;
            const float* src = &x[(size_t)m * 128 + c16 * 8];
            float4 v0 = *(const float4*)src;
            float4 v1 = *(const float4*)(src + 4);
            u4v o = {bf16pack(v0.x, v0.y), bf16pack(v0.z, v0.w),
                     bf16pack(v1.x, v1.y), bf16pack(v1.z, v1.w)};
            Asm[r * 16 + (c16 ^ (r & 7))] = o;
        }
    }
#pragma unroll
    for (int i = 0; i < NOUT * 16 / 256; ++i) Bsm[tid + i * 256] = Wt[tid + i * 256];
    __syncthreads();

    constexpr int NF = NOUT / 64;  // n-frags per wave (2 for 128, 1 for 64)
    int lane = tid & 63;
    int w = tid >> 6;
    int n0w = w * (NOUT / 4);
    int lhi = lane >> 4, llo = lane & 15;
    f32x4 acc[8][NF];
#pragma unroll
    for (int i = 0; i < 8; ++i)
#pragma unroll
        for (int j = 0; j < NF; ++j) acc[i][j] = (f32x4){0.f, 0.f, 0.f, 0.f};

#pragma unroll
    for (int ks = 0; ks < 4; ++ks) {
        int cb = ks * 4 + lhi;
        s8v bfr[NF];
#pragma unroll
        for (int j = 0; j < NF; ++j) {
            int col = n0w + j * 16 + llo;
            u4v t = Bsm[col * 16 + (cb ^ (col & 7))];
            bfr[j] = *(s8v*)&t;
        }
#pragma unroll
        for (int i = 0; i < 8; ++i) {
            int row = i * 16 + llo;
            u4v t = Asm[row * 16 + (cb ^ (row & 7))];
            s8v a = *(s8v*)&t;
#pragma unroll
            for (int j = 0; j < NF; ++j)
                acc[i][j] = __builtin_amdgcn_mfma_f32_16x16x32_bf16(a, bfr[j], acc[i][j], 0, 0, 0);
        }
    }
    __syncthreads();
#pragma unroll
    for (int i = 0; i < 8; ++i)
#pragma unroll
        for (int j = 0; j < NF; ++j)
#pragma unroll
            for (int r = 0; r < 4; ++r)
                Cst[(i * 16 + lhi * 4 + r) * NOUT + n0w + j * 16 + llo] = acc[i][j][r];
    __syncthreads();
#pragma unroll
    for (int i = 0; i < 128 * NOUT / 2 / 256; ++i) {
        int idx = tid + i * 256;
        int m = idx / (NOUT / 2), np = idx % (NOUT / 2);
        if (m0 + m < N_NODES)
            y[(size_t)(m0 + m) * (NOUT / 2) + np] =
                bf16pack(Cst[m * NOUT + 2 * np], Cst[m * NOUT + 2 * np + 1]);
    }
}

extern "C" void kernel_launch(void* const* d_in, const int* in_sizes, int n_in,
                              void* d_out, int out_size, void* d_ws, size_t ws_size,
                              hipStream_t stream) {
    const float* h_in = (const float*)d_in[0];
    const void* edges = d_in[1];
    const float* W[5] = {(const float*)d_in[2], (const float*)d_in[4], (const float*)d_in[6],
                         (const float*)d_in[8], (const float*)d_in[10]};
    const float* B[5] = {(const float*)d_in[3], (const float*)d_in[5], (const float*)d_in[7],
                         (const float*)d_in[9], (const float*)d_in[11]};

    size_t off = 0;
    auto alloc = [&](size_t bytes) {
        void* p = (char*)d_ws + off;
        off = (off + bytes + 255) & ~(size_t)255;
        return p;
    };
    int* esorted = (int*)alloc((size_t)N_EDGES * 4);            // 12.8 MB
    int* row_ptr = (int*)alloc((size_t)(N_NODES + 1) * 4);
    int* hist2 = (int*)alloc((size_t)NCHUNKS * NB * 4);
    int* base2 = (int*)alloc((size_t)NCHUNKS * NB * 4);
    int* bcount = (int*)alloc((size_t)NB * 4);
    int* boff = (int*)alloc((size_t)(NB + 1) * 4);
    int* flag = (int*)alloc(256);
    u4v* Wt[5];
    for (int l = 0; l < 5; ++l) Wt[l] = (u4v*)alloc((size_t)128 * 16 * 16);
    float* c3 = (float*)alloc(64 * 4);
    uint* C = (uint*)alloc((size_t)N_NODES * 64 * 4);           // 25.6 MB (p, bf16)
    uint* D = (uint*)alloc((size_t)N_NODES * 64 * 4);           // 25.6 MB (h', bf16)
    uint* tmp = (uint*)alloc((size_t)N_EDGES * 4);              // 12.8 MB (build; later q)
    uint* rbuf = (uint*)alloc((size_t)N_NODES * 32 * 4);        // 12.8 MB (r = agg(q))
    uint* q = tmp;  // alias: tmp dead after bucket_finalize; q written after build

    // ---- build CSR ----
    detect_fmt<<<1, 64, 0, stream>>>((const uint*)edges, flag, row_ptr);
    hipMemsetAsync(bcount, 0, (size_t)NB * 4, stream);
    part_hist<<<NCHUNKS, 256, 0, stream>>>(edges, flag, hist2, bcount);
    scan_kernel<<<1, 1024, 0, stream>>>(bcount, boff, NB);
    chunk_scan<<<NB, 256, 0, stream>>>(hist2, boff, base2);
    part_scatter<<<NCHUNKS, 256, 0, stream>>>(edges, flag, base2, tmp);
    bucket_finalize<<<NB, 256, 0, stream>>>(tmp, boff, row_ptr, esorted);

    // ---- weight prep (bf16 transpose + swizzle + c3 = b3@W4) ----
    prep_all<<<37, 256, 0, stream>>>(W[0], W[1], W[2], W[3], W[4], B[3],
                                     Wt[0], Wt[1], Wt[2], Wt[3], Wt[4], c3);

    // ---- layers 0-2: p = h@W (MFMA); h' = p + agg(p) + b ----
    const int NBLK = (N_NODES + 127) / 128;  // 782

    mfma_gemm<128, false><<<NBLK, 256, 0, stream>>>(h_in, Wt[0], C);
    agg128<<<4096, 256, 0, stream>>>(C, row_ptr, esorted, B[0], D);
    for (int l = 1; l <= 2; ++l) {
        mfma_gemm<128, true><<<NBLK, 256, 0, stream>>>(D, Wt[l], C);
        agg128<<<4096, 256, 0, stream>>>(C, row_ptr, esorted, B[l], D);
    }
    // ---- layers 3+4 restructured: p3 = h3@W3; q = p3@W4;
    //      out = q + 2*agg(q) + agg(agg(q)) + (1+deg)*c3 + b4 ----
    mfma_gemm<128, true><<<NBLK, 256, 0, stream>>>(D, Wt[3], C);   // p3
    mfma_gemm<64, true><<<NBLK, 256, 0, stream>>>(C, Wt[4], q);    // q = p3@W4
    agg64_mid<<<2048, 256, 0, stream>>>(q, row_ptr, esorted, rbuf);
    agg64_fin<<<2048, 256, 0, stream>>>(rbuf, q, row_ptr, esorted, c3, B[4], (float*)d_out);
}